// Round 9
// baseline (205.182 us; speedup 1.0000x reference)
//
#include <hip/hip_runtime.h>
#include <hip/hip_bf16.h>
#include <math.h>

typedef __bf16 bf16_t;
typedef __bf16 bf16x8 __attribute__((ext_vector_type(8)));
typedef float floatx4 __attribute__((ext_vector_type(4)));

#define NSEQ 3072
#define QKVLD 3072
#define DMODEL 1024

__device__ inline bf16x8 load8(const float* p) {
    floatx4 a = *(const floatx4*)p;
    floatx4 b = *(const floatx4*)(p + 4);
    bf16x8 r;
    r[0] = (bf16_t)a[0]; r[1] = (bf16_t)a[1]; r[2] = (bf16_t)a[2]; r[3] = (bf16_t)a[3];
    r[4] = (bf16_t)b[0]; r[5] = (bf16_t)b[1]; r[6] = (bf16_t)b[2]; r[7] = (bf16_t)b[3];
    return r;
}

// async 16B global->LDS. LDS dest = wave-uniform base + lane*16.
__device__ inline void gload16(const bf16_t* g, bf16_t* l) {
    __builtin_amdgcn_global_load_lds(
        (const __attribute__((address_space(1))) unsigned int*)g,
        (__attribute__((address_space(3))) unsigned int*)l, 16, 0, 0);
}

// ---------------------------------------------------------------------------
// prep: [0,1536) cvt x->xb ; [1536,2304) transpose Wqkv ; [2304,2560) Wout ;
//       [2560,2576) zero Mf ; 2576 zeroes Ksumf/Vsumf/hsum (contiguous).
// ---------------------------------------------------------------------------
__global__ __launch_bounds__(256) void prep_kernel(const float* __restrict__ x,
                                                   const float* __restrict__ Wqkv,
                                                   const float* __restrict__ Wout,
                                                   bf16_t* __restrict__ xb,
                                                   bf16_t* __restrict__ WqkvT,
                                                   bf16_t* __restrict__ WoutT,
                                                   float* __restrict__ Mf) {
    __shared__ float T[64][65];
    const int b = blockIdx.x, tid = threadIdx.x;
    if (b < 1536) {
        int i = b * 2048 + tid * 8;
        *(bf16x8*)(xb + i) = load8(x + i);
        return;
    }
    if (b >= 2560) {
        const floatx4 z = {0.f, 0.f, 0.f, 0.f};
        if (b < 2576) {           // Mf: 65536 f32; 16 blocks x 4096 f32
            floatx4* p = (floatx4*)(Mf + (b - 2560) * 4096);
#pragma unroll
            for (int i = 0; i < 4; ++i) p[i * 256 + tid] = z;
        } else {                  // Ksumf+Vsumf+hsum: 2064 f32 after Mf
            float* zp = Mf + 65536;
            for (int i = tid; i < 2064; i += 256) zp[i] = 0.f;
        }
        return;
    }
    const float* in; bf16_t* out; int K, N, bx, by;
    if (b < 2304) { int l = b - 1536; bx = l % 48; by = l / 48; in = Wqkv; out = WqkvT; K = 1024; N = 3072; }
    else          { int l = b - 2304; bx = l & 15; by = l >> 4; in = Wout; out = WoutT; K = 1024; N = 1024; }
    const int n0 = bx * 64, k0 = by * 64;
    const int r = tid >> 2, c0 = (tid & 3) * 16;
#pragma unroll
    for (int i = 0; i < 4; ++i) {
        floatx4 v = *(const floatx4*)(in + (size_t)(k0 + r) * N + n0 + c0 + i * 4);
        T[r][c0 + i * 4 + 0] = v[0]; T[r][c0 + i * 4 + 1] = v[1];
        T[r][c0 + i * 4 + 2] = v[2]; T[r][c0 + i * 4 + 3] = v[3];
    }
    __syncthreads();
    bf16x8 o0, o1;
#pragma unroll
    for (int i = 0; i < 8; ++i) { o0[i] = (bf16_t)T[c0 + i][r]; o1[i] = (bf16_t)T[c0 + 8 + i][r]; }
    *(bf16x8*)(out + (size_t)(n0 + r) * K + k0 + c0)     = o0;
    *(bf16x8*)(out + (size_t)(n0 + r) * K + k0 + c0 + 8) = o1;
}

// ---------------------------------------------------------------------------
// GEMM with global_load_lds staging + XOR-chunk swizzle (unchanged).
// ---------------------------------------------------------------------------
template <typename CT>
__global__ __launch_bounds__(256) void gemm_bt(const bf16_t* __restrict__ A,
                                               const bf16_t* __restrict__ BT,
                                               const float* __restrict__ bias,
                                               CT* __restrict__ C,
                                               int M, int N, int K) {
    __shared__ __attribute__((aligned(16))) bf16_t As[128 * 64];
    __shared__ __attribute__((aligned(16))) bf16_t Bs[128 * 64];
    const int tid = threadIdx.x;
    const int wave = tid >> 6, lane = tid & 63;
    const int lr = lane & 15, quad = lane >> 4;
    const int wr = (wave >> 1) * 64, wc = (wave & 1) * 64;
    const int m0 = blockIdx.y * 128, n0 = blockIdx.x * 128;
    const int srow = lane >> 3;
    const int schunk = (lane & 7) ^ srow;

    const floatx4 fzero = {0.f, 0.f, 0.f, 0.f};
    floatx4 acc[4][4];
#pragma unroll
    for (int mi = 0; mi < 4; ++mi)
#pragma unroll
        for (int ni = 0; ni < 4; ++ni) acc[mi][ni] = fzero;

    for (int kb = 0; kb < K; kb += 64) {
        __syncthreads();
#pragma unroll
        for (int it = 0; it < 4; ++it) {
            const int r0 = (wave * 4 + it) * 8;
            gload16(A + (size_t)(m0 + r0 + srow) * K + kb + schunk * 8, &As[r0 * 64]);
            gload16(BT + (size_t)(n0 + r0 + srow) * K + kb + schunk * 8, &Bs[r0 * 64]);
        }
        __syncthreads();
#pragma unroll
        for (int ch = 0; ch < 2; ++ch) {
            bf16x8 af[4], bfr[4];
#pragma unroll
            for (int mi = 0; mi < 4; ++mi)
                af[mi] = *(const bf16x8*)(&As[(wr + mi * 16 + lr) * 64 + (((ch * 4 + quad) ^ (lr & 7)) * 8)]);
#pragma unroll
            for (int ni = 0; ni < 4; ++ni)
                bfr[ni] = *(const bf16x8*)(&Bs[(wc + ni * 16 + lr) * 64 + (((ch * 4 + quad) ^ (lr & 7)) * 8)]);
#pragma unroll
            for (int mi = 0; mi < 4; ++mi)
#pragma unroll
                for (int ni = 0; ni < 4; ++ni)
                    acc[mi][ni] = __builtin_amdgcn_mfma_f32_16x16x32_bf16(af[mi], bfr[ni], acc[mi][ni], 0, 0, 0);
        }
    }

#pragma unroll
    for (int mi = 0; mi < 4; ++mi)
#pragma unroll
        for (int ni = 0; ni < 4; ++ni) {
            int n = n0 + wc + ni * 16 + lr;
            float bv = bias ? bias[n] : 0.f;
#pragma unroll
            for (int r = 0; r < 4; ++r) {
                int m = m0 + wr + mi * 16 + quad * 4 + r;
                C[(size_t)m * N + n] = (CT)(acc[mi][ni][r] + bv);
            }
        }
}

// ---------------------------------------------------------------------------
// prep2: [0,192) spiky MLP -> sfull + hsum atomics.
//        [192,384) per (head, 256-key chunk): atomicAdd K^T V into Mf[h][dk][dv],
//        plus Ksumf / Vsumf atomics.
// ---------------------------------------------------------------------------
__global__ __launch_bounds__(256) void prep2_kernel(const bf16_t* __restrict__ qkv,
                                                    const float* __restrict__ W1,
                                                    const float* __restrict__ b1,
                                                    const float* __restrict__ W2,
                                                    const float* __restrict__ b2,
                                                    float* __restrict__ sfull,
                                                    float* __restrict__ hsum,
                                                    float* __restrict__ Mf,
                                                    float* __restrict__ Ksumf,
                                                    float* __restrict__ Vsumf) {
    __shared__ __attribute__((aligned(16))) bf16_t Kt[64][72];  // [d][j]
    __shared__ __attribute__((aligned(16))) bf16_t Vt[64][72];  // [d][j]
    __shared__ float W1s[64][65];
    __shared__ float W2s[64], b1s[64];
    const int b = blockIdx.x, tid = threadIdx.x;
    if (b < 192) {
        const int h = b / 12, j = (b % 12) * 256 + tid;
        for (int i = tid; i < 4096; i += 256) W1s[i >> 6][i & 63] = W1[i];
        if (tid < 64) { W2s[tid] = W2[tid]; b1s[tid] = b1[tid]; }
        __syncthreads();
        float kv[64];
        const bf16x8* kp8 = (const bf16x8*)(qkv + (size_t)j * QKVLD + DMODEL + h * 64);
#pragma unroll
        for (int c = 0; c < 8; ++c) {
            bf16x8 v = kp8[c];
#pragma unroll
            for (int ii = 0; ii < 8; ++ii) kv[c * 8 + ii] = (float)v[ii];
        }
        float s = b2[0];
        for (int dd = 0; dd < 64; ++dd) {
            float a = b1s[dd];
#pragma unroll
            for (int d = 0; d < 64; ++d) a += kv[d] * W1s[d][dd];
            a = fmaxf(a, 0.f);
            s += a * W2s[dd];
        }
        s = 1.f / (1.f + __expf(-s));
        sfull[h * NSEQ + j] = s;
        float e = __expf(s);
#pragma unroll
        for (int off = 1; off < 64; off <<= 1) e += __shfl_xor(e, off, 64);
        if ((tid & 63) == 0) atomicAdd(&hsum[h], e);
    } else {
        const int l = b - 192;
        const int h = l / 12, c = l % 12;
        const int wave = tid >> 6, lane = tid & 63;
        const int lr = lane & 15, quad = lane >> 4;
        const int jj = tid >> 3, ch = (tid & 7) * 8;
        const floatx4 fzero = {0.f, 0.f, 0.f, 0.f};
        floatx4 macc[4];
#pragma unroll
        for (int ni = 0; ni < 4; ++ni) macc[ni] = fzero;
        float ksum = 0.f, vsum = 0.f;

        for (int st = 0; st < 4; ++st) {
            const size_t row0 = (size_t)(c * 256 + st * 64);
            bf16x8 k0 = *(const bf16x8*)(qkv + (row0 + jj) * QKVLD + DMODEL + h * 64 + ch);
            bf16x8 k1 = *(const bf16x8*)(qkv + (row0 + jj + 32) * QKVLD + DMODEL + h * 64 + ch);
            bf16x8 v0 = *(const bf16x8*)(qkv + (row0 + jj) * QKVLD + 2 * DMODEL + h * 64 + ch);
            bf16x8 v1 = *(const bf16x8*)(qkv + (row0 + jj + 32) * QKVLD + 2 * DMODEL + h * 64 + ch);
            __syncthreads();
#pragma unroll
            for (int ii = 0; ii < 8; ++ii) {
                Kt[ch + ii][jj] = k0[ii]; Kt[ch + ii][jj + 32] = k1[ii];
                Vt[ch + ii][jj] = v0[ii]; Vt[ch + ii][jj + 32] = v1[ii];
            }
            __syncthreads();
            bf16x8 a0 = *(const bf16x8*)(&Kt[wave * 16 + lr][quad * 8]);
            bf16x8 a1 = *(const bf16x8*)(&Kt[wave * 16 + lr][32 + quad * 8]);
#pragma unroll
            for (int ni = 0; ni < 4; ++ni) {
                bf16x8 b0 = *(const bf16x8*)(&Vt[ni * 16 + lr][quad * 8]);
                bf16x8 b1f = *(const bf16x8*)(&Vt[ni * 16 + lr][32 + quad * 8]);
                macc[ni] = __builtin_amdgcn_mfma_f32_16x16x32_bf16(a0, b0, macc[ni], 0, 0, 0);
                macc[ni] = __builtin_amdgcn_mfma_f32_16x16x32_bf16(a1, b1f, macc[ni], 0, 0, 0);
            }
            if (tid < 64) {
#pragma unroll
                for (int cc = 0; cc < 8; ++cc) {
                    bf16x8 kk = *(const bf16x8*)(&Kt[tid][cc * 8]);
#pragma unroll
                    for (int ii = 0; ii < 8; ++ii) ksum += (float)kk[ii];
                }
            } else if (tid < 128) {
                const int d = tid - 64;
#pragma unroll
                for (int cc = 0; cc < 8; ++cc) {
                    bf16x8 vv = *(const bf16x8*)(&Vt[d][cc * 8]);
#pragma unroll
                    for (int ii = 0; ii < 8; ++ii) vsum += (float)vv[ii];
                }
            }
        }
        float* mh = Mf + (size_t)h * 4096;
#pragma unroll
        for (int ni = 0; ni < 4; ++ni)
#pragma unroll
            for (int r = 0; r < 4; ++r)
                atomicAdd(&mh[(wave * 16 + quad * 4 + r) * 64 + ni * 16 + lr], macc[ni][r]);
        if (tid < 64) atomicAdd(&Ksumf[h * 64 + tid], ksum);
        else if (tid < 128) atomicAdd(&Vsumf[h * 64 + (tid - 64)], vsum);
    }
}

// ---------------------------------------------------------------------------
// mid: [0,128) Gt build: per (h, 128-o-tile): Gt[o][h*64+dk] = sum_dv
//      WoutT[o][h*64+dv]*M_h[dk][dv]; col 1024+h = u_h[o] = WoutT_h[o].Vs_h;
//      h==0 zeroes cols [1040,1088).
//      [128,152) Qt build: Qt[q][h*64+d] = (c/den)*q_d; col 1024+h = 1/den;
//      cols [1040,1088) zero.  c = e^{s}*0.125/hsum, den = n + c*(q.Ksum).
// ---------------------------------------------------------------------------
__global__ __launch_bounds__(256) void mid_kernel(const bf16_t* __restrict__ qkv,
                                                  const bf16_t* __restrict__ WoutT,
                                                  const float* __restrict__ Mf,
                                                  const float* __restrict__ Ksumf,
                                                  const float* __restrict__ Vsumf,
                                                  const float* __restrict__ sfull,
                                                  const float* __restrict__ hsum,
                                                  bf16_t* __restrict__ Gt,
                                                  bf16_t* __restrict__ Qt) {
    const int b = blockIdx.x, tid = threadIdx.x;
    if (b < 128) {
        __shared__ __attribute__((aligned(16))) bf16_t Ms[64][72];
        __shared__ float Vss[64];
        const int h = b >> 3, ot = b & 7;
        for (int i = tid; i < 4096; i += 256)
            Ms[i >> 6][i & 63] = (bf16_t)Mf[(size_t)h * 4096 + i];
        if (tid < 64) Vss[tid] = Vsumf[h * 64 + tid];
        __syncthreads();

        const int wave = tid >> 6, lane = tid & 63;
        const int lr = lane & 15, quad = lane >> 4;
        const floatx4 fzero = {0.f, 0.f, 0.f, 0.f};
        floatx4 acc[2][4];
#pragma unroll
        for (int mi = 0; mi < 2; ++mi)
#pragma unroll
            for (int ni = 0; ni < 4; ++ni) acc[mi][ni] = fzero;
#pragma unroll
        for (int chk = 0; chk < 2; ++chk) {
            bf16x8 af[2], bfr[4];
#pragma unroll
            for (int mi = 0; mi < 2; ++mi) {
                const int o = ot * 128 + wave * 32 + mi * 16 + lr;
                af[mi] = *(const bf16x8*)(WoutT + (size_t)o * 1024 + h * 64 + chk * 32 + quad * 8);
            }
#pragma unroll
            for (int ni = 0; ni < 4; ++ni)
                bfr[ni] = *(const bf16x8*)(&Ms[ni * 16 + lr][chk * 32 + quad * 8]);
#pragma unroll
            for (int mi = 0; mi < 2; ++mi)
#pragma unroll
                for (int ni = 0; ni < 4; ++ni)
                    acc[mi][ni] = __builtin_amdgcn_mfma_f32_16x16x32_bf16(af[mi], bfr[ni], acc[mi][ni], 0, 0, 0);
        }
#pragma unroll
        for (int mi = 0; mi < 2; ++mi)
#pragma unroll
            for (int ni = 0; ni < 4; ++ni)
#pragma unroll
                for (int r = 0; r < 4; ++r) {
                    const int o = ot * 128 + wave * 32 + mi * 16 + quad * 4 + r;
                    Gt[(size_t)o * 1088 + h * 64 + ni * 16 + lr] = (bf16_t)acc[mi][ni][r];
                }
        if (tid < 128) {
            const int o = ot * 128 + tid;
            float u = 0.f;
            const bf16x8* wp = (const bf16x8*)(WoutT + (size_t)o * 1024 + h * 64);
#pragma unroll
            for (int cc = 0; cc < 8; ++cc) {
                bf16x8 w = wp[cc];
#pragma unroll
                for (int ii = 0; ii < 8; ++ii) u += (float)w[ii] * Vss[cc * 8 + ii];
            }
            Gt[(size_t)o * 1088 + 1024 + h] = (bf16_t)u;
            if (h == 0) {
                const bf16x8 bz = {};
#pragma unroll
                for (int cc = 0; cc < 6; ++cc)
                    *(bf16x8*)(Gt + (size_t)o * 1088 + 1040 + cc * 8) = bz;
            }
        }
        if (tid >= 128 && tid < 256) {  // second half covers o rows 64..127? no:
        }
        // cover remaining o rows for u/zero: threads 128..255 handle o 128..? none
        // (only 128 o-rows per block; u done by tid<128)
    } else {
        __shared__ float Ks[1024];
        __shared__ float cinv[16];
        const int q0 = (b - 128) * 128;
        for (int i = tid; i < 1024; i += 256) Ks[i] = Ksumf[i];
        if (tid < 16) cinv[tid] = 0.125f / hsum[tid];
        __syncthreads();
        const int ql = tid >> 1, side = tid & 1;
        const int q = q0 + ql;
#pragma unroll
        for (int hh = 0; hh < 8; ++hh) {
            const int h = side * 8 + hh;
            const bf16x8* qp = (const bf16x8*)(qkv + (size_t)q * QKVLD + h * 64);
            bf16x8 qv[8];
            float dot = 0.f;
#pragma unroll
            for (int cc = 0; cc < 8; ++cc) {
                qv[cc] = qp[cc];
#pragma unroll
                for (int ii = 0; ii < 8; ++ii) dot += (float)qv[cc][ii] * Ks[h * 64 + cc * 8 + ii];
            }
            const float c = __expf(sfull[h * NSEQ + q]) * cinv[h];
            const float den = (float)NSEQ + c * dot;
            const float w = c / den;
#pragma unroll
            for (int cc = 0; cc < 8; ++cc) {
                bf16x8 o;
#pragma unroll
                for (int ii = 0; ii < 8; ++ii) o[ii] = (bf16_t)(w * (float)qv[cc][ii]);
                *(bf16x8*)(Qt + (size_t)q * 1088 + h * 64 + cc * 8) = o;
            }
            Qt[(size_t)q * 1088 + 1024 + h] = (bf16_t)(1.f / den);
        }
        const bf16x8 bz = {};
#pragma unroll
        for (int cc = 0; cc < 3; ++cc)
            *(bf16x8*)(Qt + (size_t)q * 1088 + 1040 + side * 24 + cc * 8) = bz;
    }
}

// ---------------------------------------------------------------------------
extern "C" void kernel_launch(void* const* d_in, const int* in_sizes, int n_in,
                              void* d_out, int out_size, void* d_ws, size_t ws_size,
                              hipStream_t stream) {
    const float* x    = (const float*)d_in[0];
    const float* Wqkv = (const float*)d_in[1];
    const float* W1   = (const float*)d_in[2];
    const float* b1   = (const float*)d_in[3];
    const float* W2   = (const float*)d_in[4];
    const float* b2   = (const float*)d_in[5];
    const float* Wout = (const float*)d_in[6];
    const float* bout = (const float*)d_in[7];
    float* out = (float*)d_out;

    char* ws = (char*)d_ws;
    bf16_t* WqkvT = (bf16_t*)(ws);                  // 6,291,456
    bf16_t* WoutT = (bf16_t*)(ws + 6291456);        // 2,097,152
    bf16_t* qkv   = (bf16_t*)(ws + 8388608);        // 18,874,368
    bf16_t* xb    = (bf16_t*)(ws + 27262976);       // 6,291,456 (dead after gemm1)
    bf16_t* Qt    = (bf16_t*)(ws + 33554432);       // 3072*1088*2 = 6,684,672
    bf16_t* Gt    = (bf16_t*)(ws + 40239104);       // 1024*1088*2 = 2,228,224
    float*  Mf    = (float*)(ws + 42467328);        // 262,144
    float*  Ksumf = (float*)(ws + 42729472);        // 4,096   (contiguous after Mf)
    float*  Vsumf = (float*)(ws + 42733568);        // 4,096
    float*  hsum  = (float*)(ws + 42737664);        // 64
    float*  sfull = (float*)(ws + 42737728);        // 196,608

    prep_kernel<<<2577, 256, 0, stream>>>(x, Wqkv, Wout, xb, WqkvT, WoutT, Mf);
    gemm_bt<bf16_t><<<dim3(24, 24), 256, 0, stream>>>(xb, WqkvT, nullptr, qkv, NSEQ, NSEQ, DMODEL);
    prep2_kernel<<<384, 256, 0, stream>>>(qkv, W1, b1, W2, b2, sfull, hsum, Mf, Ksumf, Vsumf);
    mid_kernel<<<152, 256, 0, stream>>>(qkv, WoutT, Mf, Ksumf, Vsumf, sfull, hsum, Gt, Qt);
    gemm_bt<float><<<dim3(8, 24), 256, 0, stream>>>(Qt, Gt, bout, out, NSEQ, DMODEL, 1088);
}

// Round 10
// 181.591 us; speedup vs baseline: 1.1299x; 1.1299x over previous
//
#include <hip/hip_runtime.h>
#include <hip/hip_bf16.h>
#include <math.h>

typedef __bf16 bf16_t;
typedef __bf16 bf16x8 __attribute__((ext_vector_type(8)));
typedef float floatx4 __attribute__((ext_vector_type(4)));

#define NSEQ 3072
#define QKVLD 3072
#define DMODEL 1024

__device__ inline bf16x8 load8(const float* p) {
    floatx4 a = *(const floatx4*)p;
    floatx4 b = *(const floatx4*)(p + 4);
    bf16x8 r;
    r[0] = (bf16_t)a[0]; r[1] = (bf16_t)a[1]; r[2] = (bf16_t)a[2]; r[3] = (bf16_t)a[3];
    r[4] = (bf16_t)b[0]; r[5] = (bf16_t)b[1]; r[6] = (bf16_t)b[2]; r[7] = (bf16_t)b[3];
    return r;
}

// async 16B global->LDS. LDS dest = wave-uniform base + lane*16.
__device__ inline void gload16(const bf16_t* g, bf16_t* l) {
    __builtin_amdgcn_global_load_lds(
        (const __attribute__((address_space(1))) unsigned int*)g,
        (__attribute__((address_space(3))) unsigned int*)l, 16, 0, 0);
}

// ---------------------------------------------------------------------------
// prep: [0,1536) cvt x->xb ; [1536,2304) transpose Wqkv ; [2304,2560) Wout ;
//       [2560,2576) zero Mf ; 2576 zeroes Ksumf/Vsumf/hsum (contiguous).
// ---------------------------------------------------------------------------
__global__ __launch_bounds__(256) void prep_kernel(const float* __restrict__ x,
                                                   const float* __restrict__ Wqkv,
                                                   const float* __restrict__ Wout,
                                                   bf16_t* __restrict__ xb,
                                                   bf16_t* __restrict__ WqkvT,
                                                   bf16_t* __restrict__ WoutT,
                                                   float* __restrict__ Mf) {
    __shared__ float T[64][65];
    const int b = blockIdx.x, tid = threadIdx.x;
    if (b < 1536) {
        int i = b * 2048 + tid * 8;
        *(bf16x8*)(xb + i) = load8(x + i);
        return;
    }
    if (b >= 2560) {
        const floatx4 z = {0.f, 0.f, 0.f, 0.f};
        if (b < 2576) {
            floatx4* p = (floatx4*)(Mf + (b - 2560) * 4096);
#pragma unroll
            for (int i = 0; i < 4; ++i) p[i * 256 + tid] = z;
        } else {
            float* zp = Mf + 65536;
            for (int i = tid; i < 2064; i += 256) zp[i] = 0.f;
        }
        return;
    }
    const float* in; bf16_t* out; int K, N, bx, by;
    if (b < 2304) { int l = b - 1536; bx = l % 48; by = l / 48; in = Wqkv; out = WqkvT; K = 1024; N = 3072; }
    else          { int l = b - 2304; bx = l & 15; by = l >> 4; in = Wout; out = WoutT; K = 1024; N = 1024; }
    const int n0 = bx * 64, k0 = by * 64;
    const int r = tid >> 2, c0 = (tid & 3) * 16;
#pragma unroll
    for (int i = 0; i < 4; ++i) {
        floatx4 v = *(const floatx4*)(in + (size_t)(k0 + r) * N + n0 + c0 + i * 4);
        T[r][c0 + i * 4 + 0] = v[0]; T[r][c0 + i * 4 + 1] = v[1];
        T[r][c0 + i * 4 + 2] = v[2]; T[r][c0 + i * 4 + 3] = v[3];
    }
    __syncthreads();
    bf16x8 o0, o1;
#pragma unroll
    for (int i = 0; i < 8; ++i) { o0[i] = (bf16_t)T[c0 + i][r]; o1[i] = (bf16_t)T[c0 + 8 + i][r]; }
    *(bf16x8*)(out + (size_t)(n0 + r) * K + k0 + c0)     = o0;
    *(bf16x8*)(out + (size_t)(n0 + r) * K + k0 + c0 + 8) = o1;
}

// ---------------------------------------------------------------------------
// GEMM, tile 128 x TN (TN = 128 or 64), BK=64. gload16 staging + XOR swizzle.
// TN=128: 2x2 waves of 64x64. TN=64: 4x1 waves of 32x64.
// ---------------------------------------------------------------------------
template <int TN, typename CT>
__global__ __launch_bounds__(256) void gemm_bt(const bf16_t* __restrict__ A,
                                               const bf16_t* __restrict__ BT,
                                               const float* __restrict__ bias,
                                               CT* __restrict__ C,
                                               int M, int N, int K) {
    constexpr int MI = (TN == 128) ? 4 : 2;
    __shared__ __attribute__((aligned(16))) bf16_t As[128 * 64];
    __shared__ __attribute__((aligned(16))) bf16_t Bs[TN * 64];
    const int tid = threadIdx.x;
    const int wave = tid >> 6, lane = tid & 63;
    const int lr = lane & 15, quad = lane >> 4;
    const int wr = (TN == 128) ? (wave >> 1) * 64 : wave * 32;
    const int wc = (TN == 128) ? (wave & 1) * 64 : 0;
    const int m0 = blockIdx.y * 128, n0 = blockIdx.x * TN;
    const int srow = lane >> 3;
    const int schunk = (lane & 7) ^ srow;

    const floatx4 fzero = {0.f, 0.f, 0.f, 0.f};
    floatx4 acc[MI][4];
#pragma unroll
    for (int mi = 0; mi < MI; ++mi)
#pragma unroll
        for (int ni = 0; ni < 4; ++ni) acc[mi][ni] = fzero;

    for (int kb = 0; kb < K; kb += 64) {
        __syncthreads();
#pragma unroll
        for (int it = 0; it < 4; ++it) {
            const int r0 = (wave * 4 + it) * 8;
            gload16(A + (size_t)(m0 + r0 + srow) * K + kb + schunk * 8, &As[r0 * 64]);
        }
#pragma unroll
        for (int it = 0; it < TN / 32; ++it) {
            const int r0 = (wave * (TN / 32) + it) * 8;
            gload16(BT + (size_t)(n0 + r0 + srow) * K + kb + schunk * 8, &Bs[r0 * 64]);
        }
        __syncthreads();
#pragma unroll
        for (int ch = 0; ch < 2; ++ch) {
            bf16x8 af[MI], bfr[4];
#pragma unroll
            for (int mi = 0; mi < MI; ++mi)
                af[mi] = *(const bf16x8*)(&As[(wr + mi * 16 + lr) * 64 + (((ch * 4 + quad) ^ (lr & 7)) * 8)]);
#pragma unroll
            for (int ni = 0; ni < 4; ++ni)
                bfr[ni] = *(const bf16x8*)(&Bs[(wc + ni * 16 + lr) * 64 + (((ch * 4 + quad) ^ (lr & 7)) * 8)]);
#pragma unroll
            for (int mi = 0; mi < MI; ++mi)
#pragma unroll
                for (int ni = 0; ni < 4; ++ni)
                    acc[mi][ni] = __builtin_amdgcn_mfma_f32_16x16x32_bf16(af[mi], bfr[ni], acc[mi][ni], 0, 0, 0);
        }
    }

#pragma unroll
    for (int mi = 0; mi < MI; ++mi)
#pragma unroll
        for (int ni = 0; ni < 4; ++ni) {
            int n = n0 + wc + ni * 16 + lr;
            float bv = bias ? bias[n] : 0.f;
#pragma unroll
            for (int r = 0; r < 4; ++r) {
                int m = m0 + wr + mi * 16 + quad * 4 + r;
                C[(size_t)m * N + n] = (CT)(acc[mi][ni][r] + bv);
            }
        }
}

// ---------------------------------------------------------------------------
// prep2: [0,192) spiky MLP -> sfull + hsum atomics.
//        [192,384) per (head, 256-key chunk): atomicAdd K^T V into Mf[h][dk][dv],
//        plus Ksumf / Vsumf atomics.
// ---------------------------------------------------------------------------
__global__ __launch_bounds__(256) void prep2_kernel(const bf16_t* __restrict__ qkv,
                                                    const float* __restrict__ W1,
                                                    const float* __restrict__ b1,
                                                    const float* __restrict__ W2,
                                                    const float* __restrict__ b2,
                                                    float* __restrict__ sfull,
                                                    float* __restrict__ hsum,
                                                    float* __restrict__ Mf,
                                                    float* __restrict__ Ksumf,
                                                    float* __restrict__ Vsumf) {
    __shared__ __attribute__((aligned(16))) bf16_t Kt[64][72];
    __shared__ __attribute__((aligned(16))) bf16_t Vt[64][72];
    __shared__ float W1s[64][65];
    __shared__ float W2s[64], b1s[64];
    const int b = blockIdx.x, tid = threadIdx.x;
    if (b < 192) {
        const int h = b / 12, j = (b % 12) * 256 + tid;
        for (int i = tid; i < 4096; i += 256) W1s[i >> 6][i & 63] = W1[i];
        if (tid < 64) { W2s[tid] = W2[tid]; b1s[tid] = b1[tid]; }
        __syncthreads();
        float kv[64];
        const bf16x8* kp8 = (const bf16x8*)(qkv + (size_t)j * QKVLD + DMODEL + h * 64);
#pragma unroll
        for (int c = 0; c < 8; ++c) {
            bf16x8 v = kp8[c];
#pragma unroll
            for (int ii = 0; ii < 8; ++ii) kv[c * 8 + ii] = (float)v[ii];
        }
        float s = b2[0];
        for (int dd = 0; dd < 64; ++dd) {
            float a = b1s[dd];
#pragma unroll
            for (int d = 0; d < 64; ++d) a += kv[d] * W1s[d][dd];
            a = fmaxf(a, 0.f);
            s += a * W2s[dd];
        }
        s = 1.f / (1.f + __expf(-s));
        sfull[h * NSEQ + j] = s;
        float e = __expf(s);
#pragma unroll
        for (int off = 1; off < 64; off <<= 1) e += __shfl_xor(e, off, 64);
        if ((tid & 63) == 0) atomicAdd(&hsum[h], e);
    } else {
        const int l = b - 192;
        const int h = l / 12, c = l % 12;
        const int wave = tid >> 6, lane = tid & 63;
        const int lr = lane & 15, quad = lane >> 4;
        const int jj = tid >> 3, ch = (tid & 7) * 8;
        const floatx4 fzero = {0.f, 0.f, 0.f, 0.f};
        floatx4 macc[4];
#pragma unroll
        for (int ni = 0; ni < 4; ++ni) macc[ni] = fzero;
        float ksum = 0.f, vsum = 0.f;

        for (int st = 0; st < 4; ++st) {
            const size_t row0 = (size_t)(c * 256 + st * 64);
            bf16x8 k0 = *(const bf16x8*)(qkv + (row0 + jj) * QKVLD + DMODEL + h * 64 + ch);
            bf16x8 k1 = *(const bf16x8*)(qkv + (row0 + jj + 32) * QKVLD + DMODEL + h * 64 + ch);
            bf16x8 v0 = *(const bf16x8*)(qkv + (row0 + jj) * QKVLD + 2 * DMODEL + h * 64 + ch);
            bf16x8 v1 = *(const bf16x8*)(qkv + (row0 + jj + 32) * QKVLD + 2 * DMODEL + h * 64 + ch);
            __syncthreads();
#pragma unroll
            for (int ii = 0; ii < 8; ++ii) {
                Kt[ch + ii][jj] = k0[ii]; Kt[ch + ii][jj + 32] = k1[ii];
                Vt[ch + ii][jj] = v0[ii]; Vt[ch + ii][jj + 32] = v1[ii];
            }
            __syncthreads();
            bf16x8 a0 = *(const bf16x8*)(&Kt[wave * 16 + lr][quad * 8]);
            bf16x8 a1 = *(const bf16x8*)(&Kt[wave * 16 + lr][32 + quad * 8]);
#pragma unroll
            for (int ni = 0; ni < 4; ++ni) {
                bf16x8 b0 = *(const bf16x8*)(&Vt[ni * 16 + lr][quad * 8]);
                bf16x8 b1f = *(const bf16x8*)(&Vt[ni * 16 + lr][32 + quad * 8]);
                macc[ni] = __builtin_amdgcn_mfma_f32_16x16x32_bf16(a0, b0, macc[ni], 0, 0, 0);
                macc[ni] = __builtin_amdgcn_mfma_f32_16x16x32_bf16(a1, b1f, macc[ni], 0, 0, 0);
            }
            if (tid < 64) {
#pragma unroll
                for (int cc = 0; cc < 8; ++cc) {
                    bf16x8 kk = *(const bf16x8*)(&Kt[tid][cc * 8]);
#pragma unroll
                    for (int ii = 0; ii < 8; ++ii) ksum += (float)kk[ii];
                }
            } else if (tid < 128) {
                const int d = tid - 64;
#pragma unroll
                for (int cc = 0; cc < 8; ++cc) {
                    bf16x8 vv = *(const bf16x8*)(&Vt[d][cc * 8]);
#pragma unroll
                    for (int ii = 0; ii < 8; ++ii) vsum += (float)vv[ii];
                }
            }
        }
        float* mh = Mf + (size_t)h * 4096;
#pragma unroll
        for (int ni = 0; ni < 4; ++ni)
#pragma unroll
            for (int r = 0; r < 4; ++r)
                atomicAdd(&mh[(wave * 16 + quad * 4 + r) * 64 + ni * 16 + lr], macc[ni][r]);
        if (tid < 64) atomicAdd(&Ksumf[h * 64 + tid], ksum);
        else if (tid < 128) atomicAdd(&Vsumf[h * 64 + (tid - 64)], vsum);
    }
}

// ---------------------------------------------------------------------------
// mid: [0,128) Gt build (unchanged).
//      [128,320) Qt build: 16 q-rows x 16 heads per block, 1 (q,h) per thread.
// ---------------------------------------------------------------------------
__global__ __launch_bounds__(256) void mid_kernel(const bf16_t* __restrict__ qkv,
                                                  const bf16_t* __restrict__ WoutT,
                                                  const float* __restrict__ Mf,
                                                  const float* __restrict__ Ksumf,
                                                  const float* __restrict__ Vsumf,
                                                  const float* __restrict__ sfull,
                                                  const float* __restrict__ hsum,
                                                  bf16_t* __restrict__ Gt,
                                                  bf16_t* __restrict__ Qt) {
    const int b = blockIdx.x, tid = threadIdx.x;
    if (b < 128) {
        __shared__ __attribute__((aligned(16))) bf16_t Ms[64][72];
        __shared__ float Vss[64];
        const int h = b >> 3, ot = b & 7;
        for (int i = tid; i < 4096; i += 256)
            Ms[i >> 6][i & 63] = (bf16_t)Mf[(size_t)h * 4096 + i];
        if (tid < 64) Vss[tid] = Vsumf[h * 64 + tid];
        __syncthreads();

        const int wave = tid >> 6, lane = tid & 63;
        const int lr = lane & 15, quad = lane >> 4;
        const floatx4 fzero = {0.f, 0.f, 0.f, 0.f};
        floatx4 acc[2][4];
#pragma unroll
        for (int mi = 0; mi < 2; ++mi)
#pragma unroll
            for (int ni = 0; ni < 4; ++ni) acc[mi][ni] = fzero;
#pragma unroll
        for (int chk = 0; chk < 2; ++chk) {
            bf16x8 af[2], bfr[4];
#pragma unroll
            for (int mi = 0; mi < 2; ++mi) {
                const int o = ot * 128 + wave * 32 + mi * 16 + lr;
                af[mi] = *(const bf16x8*)(WoutT + (size_t)o * 1024 + h * 64 + chk * 32 + quad * 8);
            }
#pragma unroll
            for (int ni = 0; ni < 4; ++ni)
                bfr[ni] = *(const bf16x8*)(&Ms[ni * 16 + lr][chk * 32 + quad * 8]);
#pragma unroll
            for (int mi = 0; mi < 2; ++mi)
#pragma unroll
                for (int ni = 0; ni < 4; ++ni)
                    acc[mi][ni] = __builtin_amdgcn_mfma_f32_16x16x32_bf16(af[mi], bfr[ni], acc[mi][ni], 0, 0, 0);
        }
#pragma unroll
        for (int mi = 0; mi < 2; ++mi)
#pragma unroll
            for (int ni = 0; ni < 4; ++ni)
#pragma unroll
                for (int r = 0; r < 4; ++r) {
                    const int o = ot * 128 + wave * 32 + mi * 16 + quad * 4 + r;
                    Gt[(size_t)o * 1088 + h * 64 + ni * 16 + lr] = (bf16_t)acc[mi][ni][r];
                }
        if (tid < 128) {
            const int o = ot * 128 + tid;
            float u = 0.f;
            const bf16x8* wp = (const bf16x8*)(WoutT + (size_t)o * 1024 + h * 64);
#pragma unroll
            for (int cc = 0; cc < 8; ++cc) {
                bf16x8 w = wp[cc];
#pragma unroll
                for (int ii = 0; ii < 8; ++ii) u += (float)w[ii] * Vss[cc * 8 + ii];
            }
            Gt[(size_t)o * 1088 + 1024 + h] = (bf16_t)u;
            if (h == 0) {
                const bf16x8 bz = {};
#pragma unroll
                for (int cc = 0; cc < 6; ++cc)
                    *(bf16x8*)(Gt + (size_t)o * 1088 + 1040 + cc * 8) = bz;
            }
        } else {
            const int o = ot * 128 + (tid - 128);
            float u = 0.f;
            const bf16x8* wp = (const bf16x8*)(WoutT + (size_t)o * 1024 + h * 64);
#pragma unroll
            for (int cc = 0; cc < 8; ++cc) {
                bf16x8 w = wp[cc];
#pragma unroll
                for (int ii = 0; ii < 8; ++ii) u += (float)w[ii] * Vss[cc * 8 + ii];
            }
            // redundant with tid<128 path only if o ranges overlapped; they don't:
            // tid-128 in [0,128) covers the same o rows -> skip store (no-op)
            (void)u;
        }
    } else {
        __shared__ float Ks[1024];
        __shared__ float cinv[16];
        const int q0 = (b - 128) * 16;
        for (int i = tid; i < 1024; i += 256) Ks[i] = Ksumf[i];
        if (tid < 16) cinv[tid] = 0.125f / hsum[tid];
        __syncthreads();
        const int q = q0 + (tid >> 4), h = tid & 15;
        const bf16x8* qp = (const bf16x8*)(qkv + (size_t)q * QKVLD + h * 64);
        bf16x8 qv[8];
        float dot = 0.f;
#pragma unroll
        for (int cc = 0; cc < 8; ++cc) {
            qv[cc] = qp[cc];
#pragma unroll
            for (int ii = 0; ii < 8; ++ii) dot += (float)qv[cc][ii] * Ks[h * 64 + cc * 8 + ii];
        }
        const float c = __expf(sfull[h * NSEQ + q]) * cinv[h];
        const float den = (float)NSEQ + c * dot;
        const float w = c / den;
#pragma unroll
        for (int cc = 0; cc < 8; ++cc) {
            bf16x8 o;
#pragma unroll
            for (int ii = 0; ii < 8; ++ii) o[ii] = (bf16_t)(w * (float)qv[cc][ii]);
            *(bf16x8*)(Qt + (size_t)q * 1088 + h * 64 + cc * 8) = o;
        }
        Qt[(size_t)q * 1088 + 1024 + h] = (bf16_t)(1.f / den);
        if (h < 6) {
            const bf16x8 bz = {};
            *(bf16x8*)(Qt + (size_t)q * 1088 + 1040 + h * 8) = bz;
        }
    }
}

// ---------------------------------------------------------------------------
extern "C" void kernel_launch(void* const* d_in, const int* in_sizes, int n_in,
                              void* d_out, int out_size, void* d_ws, size_t ws_size,
                              hipStream_t stream) {
    const float* x    = (const float*)d_in[0];
    const float* Wqkv = (const float*)d_in[1];
    const float* W1   = (const float*)d_in[2];
    const float* b1   = (const float*)d_in[3];
    const float* W2   = (const float*)d_in[4];
    const float* b2   = (const float*)d_in[5];
    const float* Wout = (const float*)d_in[6];
    const float* bout = (const float*)d_in[7];
    float* out = (float*)d_out;

    char* ws = (char*)d_ws;
    bf16_t* WqkvT = (bf16_t*)(ws);                  // 6,291,456
    bf16_t* WoutT = (bf16_t*)(ws + 6291456);        // 2,097,152
    bf16_t* qkv   = (bf16_t*)(ws + 8388608);        // 18,874,368
    bf16_t* xb    = (bf16_t*)(ws + 27262976);       // 6,291,456 (dead after gemm1)
    bf16_t* Qt    = (bf16_t*)(ws + 33554432);       // 6,684,672
    bf16_t* Gt    = (bf16_t*)(ws + 40239104);       // 2,228,224
    float*  Mf    = (float*)(ws + 42467328);        // 262,144
    float*  Ksumf = (float*)(ws + 42729472);        // 4,096
    float*  Vsumf = (float*)(ws + 42733568);        // 4,096
    float*  hsum  = (float*)(ws + 42737664);        // 64
    float*  sfull = (float*)(ws + 42737728);        // 196,608

    prep_kernel<<<2577, 256, 0, stream>>>(x, Wqkv, Wout, xb, WqkvT, WoutT, Mf);
    gemm_bt<128, bf16_t><<<dim3(24, 24), 256, 0, stream>>>(xb, WqkvT, nullptr, qkv, NSEQ, NSEQ, DMODEL);
    prep2_kernel<<<384, 256, 0, stream>>>(qkv, W1, b1, W2, b2, sfull, hsum, Mf, Ksumf, Vsumf);
    mid_kernel<<<320, 256, 0, stream>>>(qkv, WoutT, Mf, Ksumf, Vsumf, sfull, hsum, Gt, Qt);
    gemm_bt<64, float><<<dim3(16, 24), 256, 0, stream>>>(Qt, Gt, bout, out, NSEQ, DMODEL, 1088);
}

// Round 11
// 161.217 us; speedup vs baseline: 1.2727x; 1.1264x over previous
//
#include <hip/hip_runtime.h>
#include <hip/hip_bf16.h>
#include <math.h>

typedef __bf16 bf16_t;
typedef __bf16 bf16x8 __attribute__((ext_vector_type(8)));
typedef float floatx4 __attribute__((ext_vector_type(4)));

#define NSEQ 3072
#define QKVLD 3072
#define DMODEL 1024

__device__ inline bf16x8 load8(const float* p) {
    floatx4 a = *(const floatx4*)p;
    floatx4 b = *(const floatx4*)(p + 4);
    bf16x8 r;
    r[0] = (bf16_t)a[0]; r[1] = (bf16_t)a[1]; r[2] = (bf16_t)a[2]; r[3] = (bf16_t)a[3];
    r[4] = (bf16_t)b[0]; r[5] = (bf16_t)b[1]; r[6] = (bf16_t)b[2]; r[7] = (bf16_t)b[3];
    return r;
}

// async 16B global->LDS. LDS dest = wave-uniform base + lane*16.
__device__ inline void gload16(const bf16_t* g, bf16_t* l) {
    __builtin_amdgcn_global_load_lds(
        (const __attribute__((address_space(1))) unsigned int*)g,
        (__attribute__((address_space(3))) unsigned int*)l, 16, 0, 0);
}

// ---------------------------------------------------------------------------
// prep: [0,1536) cvt x->xb ; [1536,2304) transpose Wqkv ; [2304,2560) Wout ;
//       [2560,2576) zero Mf ; 2576 zeroes Ksumf/Vsumf/hsum ; 2577 builds W1T.
// ---------------------------------------------------------------------------
__global__ __launch_bounds__(256) void prep_kernel(const float* __restrict__ x,
                                                   const float* __restrict__ Wqkv,
                                                   const float* __restrict__ Wout,
                                                   const float* __restrict__ W1,
                                                   bf16_t* __restrict__ xb,
                                                   bf16_t* __restrict__ WqkvT,
                                                   bf16_t* __restrict__ WoutT,
                                                   bf16_t* __restrict__ W1T,
                                                   float* __restrict__ Mf) {
    __shared__ float T[64][65];
    const int b = blockIdx.x, tid = threadIdx.x;
    if (b < 1536) {
        int i = b * 2048 + tid * 8;
        *(bf16x8*)(xb + i) = load8(x + i);
        return;
    }
    if (b >= 2560) {
        const floatx4 z = {0.f, 0.f, 0.f, 0.f};
        if (b < 2576) {
            floatx4* p = (floatx4*)(Mf + (b - 2560) * 4096);
#pragma unroll
            for (int i = 0; i < 4; ++i) p[i * 256 + tid] = z;
        } else if (b == 2576) {
            float* zp = Mf + 65536;
            for (int i = tid; i < 2064; i += 256) zp[i] = 0.f;
        } else {  // W1T[dd][d] = W1[d][dd], bf16
            for (int i = tid; i < 4096; i += 256) {
                const int dd = i >> 6, d = i & 63;
                W1T[i] = (bf16_t)W1[d * 64 + dd];
            }
        }
        return;
    }
    const float* in; bf16_t* out; int K, N, bx, by;
    if (b < 2304) { int l = b - 1536; bx = l % 48; by = l / 48; in = Wqkv; out = WqkvT; K = 1024; N = 3072; }
    else          { int l = b - 2304; bx = l & 15; by = l >> 4; in = Wout; out = WoutT; K = 1024; N = 1024; }
    const int n0 = bx * 64, k0 = by * 64;
    const int r = tid >> 2, c0 = (tid & 3) * 16;
#pragma unroll
    for (int i = 0; i < 4; ++i) {
        floatx4 v = *(const floatx4*)(in + (size_t)(k0 + r) * N + n0 + c0 + i * 4);
        T[r][c0 + i * 4 + 0] = v[0]; T[r][c0 + i * 4 + 1] = v[1];
        T[r][c0 + i * 4 + 2] = v[2]; T[r][c0 + i * 4 + 3] = v[3];
    }
    __syncthreads();
    bf16x8 o0, o1;
#pragma unroll
    for (int i = 0; i < 8; ++i) { o0[i] = (bf16_t)T[c0 + i][r]; o1[i] = (bf16_t)T[c0 + 8 + i][r]; }
    *(bf16x8*)(out + (size_t)(n0 + r) * K + k0 + c0)     = o0;
    *(bf16x8*)(out + (size_t)(n0 + r) * K + k0 + c0 + 8) = o1;
}

// ---------------------------------------------------------------------------
// GEMM, tile 128 x TN (TN = 128 or 64), BK=64. gload16 staging + XOR swizzle.
// ---------------------------------------------------------------------------
template <int TN, typename CT>
__global__ __launch_bounds__(256) void gemm_bt(const bf16_t* __restrict__ A,
                                               const bf16_t* __restrict__ BT,
                                               const float* __restrict__ bias,
                                               CT* __restrict__ C,
                                               int M, int N, int K) {
    constexpr int MI = (TN == 128) ? 4 : 2;
    __shared__ __attribute__((aligned(16))) bf16_t As[128 * 64];
    __shared__ __attribute__((aligned(16))) bf16_t Bs[TN * 64];
    const int tid = threadIdx.x;
    const int wave = tid >> 6, lane = tid & 63;
    const int lr = lane & 15, quad = lane >> 4;
    const int wr = (TN == 128) ? (wave >> 1) * 64 : wave * 32;
    const int wc = (TN == 128) ? (wave & 1) * 64 : 0;
    const int m0 = blockIdx.y * 128, n0 = blockIdx.x * TN;
    const int srow = lane >> 3;
    const int schunk = (lane & 7) ^ srow;

    const floatx4 fzero = {0.f, 0.f, 0.f, 0.f};
    floatx4 acc[MI][4];
#pragma unroll
    for (int mi = 0; mi < MI; ++mi)
#pragma unroll
        for (int ni = 0; ni < 4; ++ni) acc[mi][ni] = fzero;

    for (int kb = 0; kb < K; kb += 64) {
        __syncthreads();
#pragma unroll
        for (int it = 0; it < 4; ++it) {
            const int r0 = (wave * 4 + it) * 8;
            gload16(A + (size_t)(m0 + r0 + srow) * K + kb + schunk * 8, &As[r0 * 64]);
        }
#pragma unroll
        for (int it = 0; it < TN / 32; ++it) {
            const int r0 = (wave * (TN / 32) + it) * 8;
            gload16(BT + (size_t)(n0 + r0 + srow) * K + kb + schunk * 8, &Bs[r0 * 64]);
        }
        __syncthreads();
#pragma unroll
        for (int ch = 0; ch < 2; ++ch) {
            bf16x8 af[MI], bfr[4];
#pragma unroll
            for (int mi = 0; mi < MI; ++mi)
                af[mi] = *(const bf16x8*)(&As[(wr + mi * 16 + lr) * 64 + (((ch * 4 + quad) ^ (lr & 7)) * 8)]);
#pragma unroll
            for (int ni = 0; ni < 4; ++ni)
                bfr[ni] = *(const bf16x8*)(&Bs[(wc + ni * 16 + lr) * 64 + (((ch * 4 + quad) ^ (lr & 7)) * 8)]);
#pragma unroll
            for (int mi = 0; mi < MI; ++mi)
#pragma unroll
                for (int ni = 0; ni < 4; ++ni)
                    acc[mi][ni] = __builtin_amdgcn_mfma_f32_16x16x32_bf16(af[mi], bfr[ni], acc[mi][ni], 0, 0, 0);
        }
    }

#pragma unroll
    for (int mi = 0; mi < MI; ++mi)
#pragma unroll
        for (int ni = 0; ni < 4; ++ni) {
            int n = n0 + wc + ni * 16 + lr;
            float bv = bias ? bias[n] : 0.f;
#pragma unroll
            for (int r = 0; r < 4; ++r) {
                int m = m0 + wr + mi * 16 + quad * 4 + r;
                C[(size_t)m * N + n] = (CT)(acc[mi][ni][r] + bv);
            }
        }
}

// ---------------------------------------------------------------------------
// prep2: [0,192) spiky MLP via MFMA: per (h, 256-j chunk), A-frags straight
//        from qkv (row-contiguous), B-frags from W1T; s = hidden@W2 in-reg.
//        [192,384) per (head, 256-key chunk): atomicAdd K^T V into Mf + sums.
// ---------------------------------------------------------------------------
__global__ __launch_bounds__(256) void prep2_kernel(const bf16_t* __restrict__ qkv,
                                                    const bf16_t* __restrict__ W1T,
                                                    const float* __restrict__ b1,
                                                    const float* __restrict__ W2,
                                                    const float* __restrict__ b2,
                                                    float* __restrict__ sfull,
                                                    float* __restrict__ hsum,
                                                    float* __restrict__ Mf,
                                                    float* __restrict__ Ksumf,
                                                    float* __restrict__ Vsumf) {
    const int b = blockIdx.x, tid = threadIdx.x;
    const int wave = tid >> 6, lane = tid & 63;
    const int lr = lane & 15, quad = lane >> 4;
    if (b < 192) {
        const int h = b / 12;
        const int jbase = (b % 12) * 256 + wave * 64;
        const bf16_t* kb = qkv + DMODEL + h * 64;
        const floatx4 fzero = {0.f, 0.f, 0.f, 0.f};
        floatx4 acc[4][4];
#pragma unroll
        for (int mi = 0; mi < 4; ++mi)
#pragma unroll
            for (int ni = 0; ni < 4; ++ni) acc[mi][ni] = fzero;
#pragma unroll
        for (int ch = 0; ch < 2; ++ch) {
            bf16x8 af[4], bfr[4];
#pragma unroll
            for (int mi = 0; mi < 4; ++mi)
                af[mi] = *(const bf16x8*)(kb + (size_t)(jbase + mi * 16 + lr) * QKVLD + ch * 32 + quad * 8);
#pragma unroll
            for (int ni = 0; ni < 4; ++ni)
                bfr[ni] = *(const bf16x8*)(W1T + (ni * 16 + lr) * 64 + ch * 32 + quad * 8);
#pragma unroll
            for (int mi = 0; mi < 4; ++mi)
#pragma unroll
                for (int ni = 0; ni < 4; ++ni)
                    acc[mi][ni] = __builtin_amdgcn_mfma_f32_16x16x32_bf16(af[mi], bfr[ni], acc[mi][ni], 0, 0, 0);
        }
        float b1v[4], W2v[4];
#pragma unroll
        for (int ni = 0; ni < 4; ++ni) { b1v[ni] = b1[ni * 16 + lr]; W2v[ni] = W2[ni * 16 + lr]; }
        const float b2v = b2[0];
        float eh = 0.f;
#pragma unroll
        for (int mi = 0; mi < 4; ++mi)
#pragma unroll
            for (int r = 0; r < 4; ++r) {
                float p = 0.f;
#pragma unroll
                for (int ni = 0; ni < 4; ++ni)
                    p += fmaxf(acc[mi][ni][r] + b1v[ni], 0.f) * W2v[ni];
#pragma unroll
                for (int off = 1; off < 16; off <<= 1) p += __shfl_xor(p, off, 64);
                const float s = 1.f / (1.f + __expf(-(b2v + p)));
                if (lr == 0) {
                    sfull[h * NSEQ + jbase + mi * 16 + quad * 4 + r] = s;
                    eh += __expf(s);
                }
            }
        // eh held by lr==0 lanes (4 per wave: quad 0..3); reduce across quads
        eh += __shfl_xor(eh, 16, 64);
        eh += __shfl_xor(eh, 32, 64);
        if (lane == 0) atomicAdd(&hsum[h], eh);
    } else {
        __shared__ __attribute__((aligned(16))) bf16_t Kt[64][72];
        __shared__ __attribute__((aligned(16))) bf16_t Vt[64][72];
        const int l = b - 192;
        const int h = l / 12, c = l % 12;
        const int jj = tid >> 3, ch = (tid & 7) * 8;
        const floatx4 fzero = {0.f, 0.f, 0.f, 0.f};
        floatx4 macc[4];
#pragma unroll
        for (int ni = 0; ni < 4; ++ni) macc[ni] = fzero;
        float ksum = 0.f, vsum = 0.f;

        for (int st = 0; st < 4; ++st) {
            const size_t row0 = (size_t)(c * 256 + st * 64);
            bf16x8 k0 = *(const bf16x8*)(qkv + (row0 + jj) * QKVLD + DMODEL + h * 64 + ch);
            bf16x8 k1 = *(const bf16x8*)(qkv + (row0 + jj + 32) * QKVLD + DMODEL + h * 64 + ch);
            bf16x8 v0 = *(const bf16x8*)(qkv + (row0 + jj) * QKVLD + 2 * DMODEL + h * 64 + ch);
            bf16x8 v1 = *(const bf16x8*)(qkv + (row0 + jj + 32) * QKVLD + 2 * DMODEL + h * 64 + ch);
            __syncthreads();
#pragma unroll
            for (int ii = 0; ii < 8; ++ii) {
                Kt[ch + ii][jj] = k0[ii]; Kt[ch + ii][jj + 32] = k1[ii];
                Vt[ch + ii][jj] = v0[ii]; Vt[ch + ii][jj + 32] = v1[ii];
            }
            __syncthreads();
            bf16x8 a0 = *(const bf16x8*)(&Kt[wave * 16 + lr][quad * 8]);
            bf16x8 a1 = *(const bf16x8*)(&Kt[wave * 16 + lr][32 + quad * 8]);
#pragma unroll
            for (int ni = 0; ni < 4; ++ni) {
                bf16x8 b0 = *(const bf16x8*)(&Vt[ni * 16 + lr][quad * 8]);
                bf16x8 b1f = *(const bf16x8*)(&Vt[ni * 16 + lr][32 + quad * 8]);
                macc[ni] = __builtin_amdgcn_mfma_f32_16x16x32_bf16(a0, b0, macc[ni], 0, 0, 0);
                macc[ni] = __builtin_amdgcn_mfma_f32_16x16x32_bf16(a1, b1f, macc[ni], 0, 0, 0);
            }
            if (tid < 64) {
#pragma unroll
                for (int cc = 0; cc < 8; ++cc) {
                    bf16x8 kk = *(const bf16x8*)(&Kt[tid][cc * 8]);
#pragma unroll
                    for (int ii = 0; ii < 8; ++ii) ksum += (float)kk[ii];
                }
            } else if (tid < 128) {
                const int d = tid - 64;
#pragma unroll
                for (int cc = 0; cc < 8; ++cc) {
                    bf16x8 vv = *(const bf16x8*)(&Vt[d][cc * 8]);
#pragma unroll
                    for (int ii = 0; ii < 8; ++ii) vsum += (float)vv[ii];
                }
            }
        }
        float* mh = Mf + (size_t)h * 4096;
#pragma unroll
        for (int ni = 0; ni < 4; ++ni)
#pragma unroll
            for (int r = 0; r < 4; ++r)
                atomicAdd(&mh[(wave * 16 + quad * 4 + r) * 64 + ni * 16 + lr], macc[ni][r]);
        if (tid < 64) atomicAdd(&Ksumf[h * 64 + tid], ksum);
        else if (tid < 128) atomicAdd(&Vsumf[h * 64 + (tid - 64)], vsum);
    }
}

// ---------------------------------------------------------------------------
// mid: [0,128) Gt build. [128,320) Qt build: 16 q x 16 h per block.
// ---------------------------------------------------------------------------
__global__ __launch_bounds__(256) void mid_kernel(const bf16_t* __restrict__ qkv,
                                                  const bf16_t* __restrict__ WoutT,
                                                  const float* __restrict__ Mf,
                                                  const float* __restrict__ Ksumf,
                                                  const float* __restrict__ Vsumf,
                                                  const float* __restrict__ sfull,
                                                  const float* __restrict__ hsum,
                                                  bf16_t* __restrict__ Gt,
                                                  bf16_t* __restrict__ Qt) {
    const int b = blockIdx.x, tid = threadIdx.x;
    if (b < 128) {
        __shared__ __attribute__((aligned(16))) bf16_t Ms[64][72];
        __shared__ float Vss[64];
        const int h = b >> 3, ot = b & 7;
        for (int i = tid; i < 4096; i += 256)
            Ms[i >> 6][i & 63] = (bf16_t)Mf[(size_t)h * 4096 + i];
        if (tid < 64) Vss[tid] = Vsumf[h * 64 + tid];
        __syncthreads();

        const int wave = tid >> 6, lane = tid & 63;
        const int lr = lane & 15, quad = lane >> 4;
        const floatx4 fzero = {0.f, 0.f, 0.f, 0.f};
        floatx4 acc[2][4];
#pragma unroll
        for (int mi = 0; mi < 2; ++mi)
#pragma unroll
            for (int ni = 0; ni < 4; ++ni) acc[mi][ni] = fzero;
#pragma unroll
        for (int chk = 0; chk < 2; ++chk) {
            bf16x8 af[2], bfr[4];
#pragma unroll
            for (int mi = 0; mi < 2; ++mi) {
                const int o = ot * 128 + wave * 32 + mi * 16 + lr;
                af[mi] = *(const bf16x8*)(WoutT + (size_t)o * 1024 + h * 64 + chk * 32 + quad * 8);
            }
#pragma unroll
            for (int ni = 0; ni < 4; ++ni)
                bfr[ni] = *(const bf16x8*)(&Ms[ni * 16 + lr][chk * 32 + quad * 8]);
#pragma unroll
            for (int mi = 0; mi < 2; ++mi)
#pragma unroll
                for (int ni = 0; ni < 4; ++ni)
                    acc[mi][ni] = __builtin_amdgcn_mfma_f32_16x16x32_bf16(af[mi], bfr[ni], acc[mi][ni], 0, 0, 0);
        }
#pragma unroll
        for (int mi = 0; mi < 2; ++mi)
#pragma unroll
            for (int ni = 0; ni < 4; ++ni)
#pragma unroll
                for (int r = 0; r < 4; ++r) {
                    const int o = ot * 128 + wave * 32 + mi * 16 + quad * 4 + r;
                    Gt[(size_t)o * 1088 + h * 64 + ni * 16 + lr] = (bf16_t)acc[mi][ni][r];
                }
        if (tid < 128) {
            const int o = ot * 128 + tid;
            float u = 0.f;
            const bf16x8* wp = (const bf16x8*)(WoutT + (size_t)o * 1024 + h * 64);
#pragma unroll
            for (int cc = 0; cc < 8; ++cc) {
                bf16x8 w = wp[cc];
#pragma unroll
                for (int ii = 0; ii < 8; ++ii) u += (float)w[ii] * Vss[cc * 8 + ii];
            }
            Gt[(size_t)o * 1088 + 1024 + h] = (bf16_t)u;
            if (h == 0) {
                const bf16x8 bz = {};
#pragma unroll
                for (int cc = 0; cc < 6; ++cc)
                    *(bf16x8*)(Gt + (size_t)o * 1088 + 1040 + cc * 8) = bz;
            }
        }
    } else {
        __shared__ float Ks[1024];
        __shared__ float cinv[16];
        const int q0 = (b - 128) * 16;
        for (int i = tid; i < 1024; i += 256) Ks[i] = Ksumf[i];
        if (tid < 16) cinv[tid] = 0.125f / hsum[tid];
        __syncthreads();
        const int q = q0 + (tid >> 4), h = tid & 15;
        const bf16x8* qp = (const bf16x8*)(qkv + (size_t)q * QKVLD + h * 64);
        bf16x8 qv[8];
        float dot = 0.f;
#pragma unroll
        for (int cc = 0; cc < 8; ++cc) {
            qv[cc] = qp[cc];
#pragma unroll
            for (int ii = 0; ii < 8; ++ii) dot += (float)qv[cc][ii] * Ks[h * 64 + cc * 8 + ii];
        }
        const float c = __expf(sfull[h * NSEQ + q]) * cinv[h];
        const float den = (float)NSEQ + c * dot;
        const float w = c / den;
#pragma unroll
        for (int cc = 0; cc < 8; ++cc) {
            bf16x8 o;
#pragma unroll
            for (int ii = 0; ii < 8; ++ii) o[ii] = (bf16_t)(w * (float)qv[cc][ii]);
            *(bf16x8*)(Qt + (size_t)q * 1088 + h * 64 + cc * 8) = o;
        }
        Qt[(size_t)q * 1088 + 1024 + h] = (bf16_t)(1.f / den);
        if (h < 6) {
            const bf16x8 bz = {};
            *(bf16x8*)(Qt + (size_t)q * 1088 + 1040 + h * 8) = bz;
        }
    }
}

// ---------------------------------------------------------------------------
extern "C" void kernel_launch(void* const* d_in, const int* in_sizes, int n_in,
                              void* d_out, int out_size, void* d_ws, size_t ws_size,
                              hipStream_t stream) {
    const float* x    = (const float*)d_in[0];
    const float* Wqkv = (const float*)d_in[1];
    const float* W1   = (const float*)d_in[2];
    const float* b1   = (const float*)d_in[3];
    const float* W2   = (const float*)d_in[4];
    const float* b2   = (const float*)d_in[5];
    const float* Wout = (const float*)d_in[6];
    const float* bout = (const float*)d_in[7];
    float* out = (float*)d_out;

    char* ws = (char*)d_ws;
    bf16_t* WqkvT = (bf16_t*)(ws);                  // 6,291,456
    bf16_t* WoutT = (bf16_t*)(ws + 6291456);        // 2,097,152
    bf16_t* qkv   = (bf16_t*)(ws + 8388608);        // 18,874,368
    bf16_t* xb    = (bf16_t*)(ws + 27262976);       // 6,291,456 (dead after gemm1)
    bf16_t* Qt    = (bf16_t*)(ws + 33554432);       // 6,684,672
    bf16_t* Gt    = (bf16_t*)(ws + 40239104);       // 2,228,224
    float*  Mf    = (float*)(ws + 42467328);        // 262,144
    float*  Ksumf = (float*)(ws + 42729472);        // 4,096
    float*  Vsumf = (float*)(ws + 42733568);        // 4,096
    float*  hsum  = (float*)(ws + 42737664);        // 64
    float*  sfull = (float*)(ws + 42737728);        // 196,608
    bf16_t* W1T   = (bf16_t*)(ws + 42934336);       // 8,192

    prep_kernel<<<2578, 256, 0, stream>>>(x, Wqkv, Wout, W1, xb, WqkvT, WoutT, W1T, Mf);
    gemm_bt<128, bf16_t><<<dim3(24, 24), 256, 0, stream>>>(xb, WqkvT, nullptr, qkv, NSEQ, NSEQ, DMODEL);
    prep2_kernel<<<384, 256, 0, stream>>>(qkv, W1T, b1, W2, b2, sfull, hsum, Mf, Ksumf, Vsumf);
    mid_kernel<<<320, 256, 0, stream>>>(qkv, WoutT, Mf, Ksumf, Vsumf, sfull, hsum, Gt, Qt);
    gemm_bt<64, float><<<dim3(16, 24), 256, 0, stream>>>(Qt, Gt, bout, out, NSEQ, DMODEL, 1088);
}